// Round 3
// baseline (533.440 us; speedup 1.0000x reference)
//
#include <hip/hip_runtime.h>
#include <hip/hip_bf16.h>
#include <stdint.h>

#define SEQ   2048
#define BATCH 2
#define DIM   1024
#define NHEAD 16
#define HD    64
#define NT    (BATCH*SEQ)   // 4096 tokens
#define N3    (3*DIM)       // 3072
#define QSCALE 0.180336881f // 0.125 * log2(e)

typedef __attribute__((ext_vector_type(4)))  float f32x4;
typedef __attribute__((ext_vector_type(16))) float f32x16;
typedef __attribute__((ext_vector_type(8)))  short s16x8;
typedef __attribute__((ext_vector_type(4)))  unsigned short u16x4;
typedef __attribute__((ext_vector_type(4)))  unsigned int u32x4;

__device__ __forceinline__ unsigned short f2bf(float x){
  union { float f; uint32_t u; } v; v.f = x;
  return (unsigned short)((v.u + 0x7fffu + ((v.u >> 16) & 1u)) >> 16);
}
__device__ __forceinline__ float bf2f(unsigned short u){
  union { uint32_t u; float f; } v; v.u = ((uint32_t)u) << 16;
  return v.f;
}
__device__ __forceinline__ unsigned int cvtpk(float lo, float hi){
  unsigned int r;
  asm("v_cvt_pk_bf16_f32 %0, %1, %2" : "=v"(r) : "v"(lo), "v"(hi));
  return r;
}
__device__ __forceinline__ void gload16(const void* g, void* l){
  __builtin_amdgcn_global_load_lds((const __attribute__((address_space(1))) void*)g,
                                   (__attribute__((address_space(3))) void*)l, 16, 0, 0);
}
__device__ __forceinline__ f32x16 zero16(){
  f32x16 z;
#pragma unroll
  for (int i=0;i<16;i++) z[i]=0.f;
  return z;
}
#define MFMA(a,b,c)   __builtin_amdgcn_mfma_f32_16x16x32_bf16((a),(b),(c),0,0,0)
#define MFMA32(a,b,c) __builtin_amdgcn_mfma_f32_32x32x16_bf16((a),(b),(c),0,0,0)

// ---------------- split fp32 -> bf16 hi/lo ----------------
__global__ __launch_bounds__(256) void k_split(const float* __restrict__ in,
                                               unsigned short* __restrict__ hi,
                                               unsigned short* __restrict__ lo, int n4){
  int i = blockIdx.x*256 + threadIdx.x;
  if (i >= n4) return;
  f32x4 v = ((const f32x4*)in)[i];
  u16x4 h, l;
#pragma unroll
  for (int e=0;e<4;e++){ unsigned short hh = f2bf(v[e]); h[e]=hh; l[e]=f2bf(v[e]-bf2f(hh)); }
  ((u16x4*)hi)[i]=h; ((u16x4*)lo)[i]=l;
}

// ---------------- transpose + split: in[R][C] -> outT[C][R] ----------------
__global__ void k_splitT(const float* __restrict__ in,
                         unsigned short* __restrict__ hiT,
                         unsigned short* __restrict__ loT, int R, int C){
  __shared__ float t[32][33];
  int c0 = blockIdx.x*32, r0 = blockIdx.y*32;
  int tx = threadIdx.x, ty = threadIdx.y;
#pragma unroll
  for (int j=0;j<32;j+=8) t[ty+j][tx] = in[(size_t)(r0+ty+j)*C + c0+tx];
  __syncthreads();
#pragma unroll
  for (int j=0;j<32;j+=8){
    float v = t[tx][ty+j];
    unsigned short hh = f2bf(v);
    size_t o = (size_t)(c0+ty+j)*R + r0+tx;
    hiT[o]=hh; loT[o]=f2bf(v-bf2f(hh));
  }
}

// ---------------- bf16 GEMM: C[M,N] = A[M,K] * B^T[N,K] + bias ----------------
// SPLIT=1: 3-MFMA split-bf16 (hi/lo) product. SPLIT=0: plain bf16.
// EPI==0: N=3072, epilogue = bias + RoPE (q scaled by QSCALE), scatter q,k [bh][t][d], V^T [bh][d][t]
// EPI==1: N=1024, epilogue = bias, write fp32 out
template<int EPI, int SPLIT>
__global__ __launch_bounds__(256) void k_gemm(
    const unsigned short* __restrict__ Ahi, const unsigned short* __restrict__ Alo,
    const unsigned short* __restrict__ Bhi, const unsigned short* __restrict__ Blo,
    const float* __restrict__ bias,
    unsigned short* __restrict__ qb, unsigned short* __restrict__ kbp,
    unsigned short* __restrict__ vbp, float* __restrict__ outp){
  __shared__ unsigned short sA[SPLIT+1][128*32];
  __shared__ unsigned short sB[SPLIT+1][128*32];
  const int tid = threadIdx.x;
  const int w = tid>>6, lane = tid&63;
  const int lr = lane&15, lk = lane>>4;
  const int wm = (w>>1)*64, wn = (w&1)*64;
  const int m0 = blockIdx.y*128, n0 = blockIdx.x*128;

  f32x4 acc[4][4];
#pragma unroll
  for (int m=0;m<4;m++)
#pragma unroll
    for (int n=0;n<4;n++) acc[m][n] = (f32x4){0.f,0.f,0.f,0.f};

  const int srow  = lane>>2;       // row within 16-row chunk
  const int sbyte = (lane&3)*16;   // byte col within 64B row

  for (int kt=0; kt<1024/32; ++kt){
    const int k0 = kt*32;
#pragma unroll
    for (int cc=0; cc<2; ++cc){
      const int chunk = w*2+cc;
      const int row = chunk*16 + srow;
      const size_t aoff = ((size_t)(m0+row)*1024 + k0)*2 + sbyte;
      const size_t boff = ((size_t)(n0+row)*1024 + k0)*2 + sbyte;
      gload16((const char*)Ahi + aoff, (char*)(&sA[0][0]) + chunk*1024);
      gload16((const char*)Bhi + boff, (char*)(&sB[0][0]) + chunk*1024);
      if constexpr (SPLIT){
        gload16((const char*)Alo + aoff, (char*)(&sA[1][0]) + chunk*1024);
        gload16((const char*)Blo + boff, (char*)(&sB[1][0]) + chunk*1024);
      }
    }
    __syncthreads();

    s16x8 ah[4], al[4], bh[4], bl[4];
#pragma unroll
    for (int m=0;m<4;m++){
      const int off = (wm + m*16 + lr)*64 + lk*16;
      ah[m] = *(const s16x8*)((const char*)(&sA[0][0]) + off);
      if constexpr (SPLIT) al[m] = *(const s16x8*)((const char*)(&sA[1][0]) + off);
    }
#pragma unroll
    for (int n=0;n<4;n++){
      const int off = (wn + n*16 + lr)*64 + lk*16;
      bh[n] = *(const s16x8*)((const char*)(&sB[0][0]) + off);
      if constexpr (SPLIT) bl[n] = *(const s16x8*)((const char*)(&sB[1][0]) + off);
    }
#pragma unroll
    for (int m=0;m<4;m++)
#pragma unroll
      for (int n=0;n<4;n++){
        acc[m][n] = MFMA(ah[m], bh[n], acc[m][n]);
        if constexpr (SPLIT){
          acc[m][n] = MFMA(ah[m], bl[n], acc[m][n]);
          acc[m][n] = MFMA(al[m], bh[n], acc[m][n]);
        }
      }
    __syncthreads();
  }

  // epilogue
#pragma unroll
  for (int m=0;m<4;m++)
#pragma unroll
    for (int n=0;n<4;n++)
#pragma unroll
      for (int r=0;r<4;r++){
        const int gm = m0 + wm + m*16 + lk*4 + r;
        const int gn = n0 + wn + n*16 + lr;
        float val = acc[m][n][r] + bias[gn];
        if (EPI == 0){
          const int three = gn>>10, rem = gn&1023, h = rem>>6, d = rem&63;
          const int b = gm>>11, t = gm&2047;
          const float partner = __shfl_xor(val, 1);
          const size_t hb_base = ((size_t)(b*NHEAD + h))*SEQ*HD;
          if (three < 2){
            const float fi = (float)(d>>1);
            const float ang = (float)t * exp2f(fi * -0.41524101186f); // -log2(10000)/32
            float sn, cs; sincosf(ang, &sn, &cs);
            float o;
            if (d & 1) o = partner*sn + val*cs;   // im' = re*sin + im*cos
            else       o = val*cs - partner*sn;   // re' = re*cos - im*sin
            const size_t dst = hb_base + (size_t)t*HD + d;
            if (three==0) qb[dst] = f2bf(o*QSCALE);
            else          kbp[dst] = f2bf(o);
          } else {
            // V stored TRANSPOSED: [bh][d][t]
            vbp[hb_base + (size_t)d*SEQ + t] = f2bf(val);
          }
        } else {
          outp[(size_t)gm*DIM + gn] = val;
        }
      }
}

// ---------------- flash attention: 32x32 MFMA, swapped QK^T, in-reg softmax ----------------
// 4 waves/block, wave owns 32 q rows. K direct from global; V^T direct from global.
// No LDS tiles, no barriers.
__global__ __launch_bounds__(256) void k_attn(const unsigned short* __restrict__ qb,
                                              const unsigned short* __restrict__ kb,
                                              const unsigned short* __restrict__ vTb,
                                              unsigned short* __restrict__ ao){
  __shared__ float l_tab[4][32];
  // XCD swizzle: 512 blocks, group 64 consecutive work items (4 bh) per XCD
  const int flat = blockIdx.x;
  const int wi = (flat & 7)*64 + (flat >> 3);
  const int bh = wi >> 4, qt = wi & 15;
  const int wid = threadIdx.x >> 6, lane = threadIdx.x & 63;
  const int col = lane & 31, hi = lane >> 5;
  const size_t base = (size_t)bh*SEQ*HD;
  const int q0 = qt*128 + wid*32;

  // Q fragments (B-operand): Q[q0+col][hb*16 + hi*8 + 0..7], pre-scaled by QSCALE
  s16x8 qf[4];
  {
    const unsigned short* qp = qb + base + (size_t)(q0+col)*HD + hi*8;
#pragma unroll
    for (int hb=0;hb<4;hb++) qf[hb] = *(const s16x8*)(qp + hb*16);
  }

  f32x16 o0 = zero16(), o1 = zero16();
  float m = -INFINITY, l = 0.f;

  for (int kv0 = 0; kv0 < SEQ; kv0 += 64){
    // ---- QK^T: S^T[kv][q], A=K (i=kv=col), B=Q (j=q=col) ----
    s16x8 kf0[4], kf1[4];
    {
      const unsigned short* kp0 = kb + base + (size_t)(kv0+col)*HD + hi*8;
      const unsigned short* kp1 = kp0 + 32*HD;
#pragma unroll
      for (int hb=0;hb<4;hb++){
        kf0[hb] = *(const s16x8*)(kp0 + hb*16);
        kf1[hb] = *(const s16x8*)(kp1 + hb*16);
      }
    }
    f32x16 a0 = zero16(), a1 = zero16();
#pragma unroll
    for (int hb=0;hb<4;hb++){
      a0 = MFMA32(kf0[hb], qf[hb], a0);
      a1 = MFMA32(kf1[hb], qf[hb], a1);
    }

    // ---- issue V^T loads early (latency hidden under softmax) ----
    s16x8 vf0[4], vf1[4];
    {
      const unsigned short* vp0 = vTb + base + (size_t)col*SEQ + kv0 + hi*8;
      const unsigned short* vp1 = vp0 + (size_t)32*SEQ;
#pragma unroll
      for (int mk=0;mk<4;mk++){
        vf0[mk] = *(const s16x8*)(vp0 + mk*16);
        vf1[mk] = *(const s16x8*)(vp1 + mk*16);
      }
    }

    // ---- in-register online softmax (log2 domain; scale folded into Q) ----
    float pm = a0[0];
#pragma unroll
    for (int i=1;i<16;i++) pm = fmaxf(pm, a0[i]);
#pragma unroll
    for (int i=0;i<16;i++) pm = fmaxf(pm, a1[i]);
    pm = fmaxf(pm, __shfl_xor(pm, 32));

    if (!__all(pm - m <= 8.0f)){   // T13 defer-max
      const float mn = fmaxf(m, pm);
      const float al = __builtin_amdgcn_exp2f(m - mn);
      l *= al;
#pragma unroll
      for (int i=0;i<16;i++){ o0[i] *= al; o1[i] *= al; }
      m = mn;
    }
#pragma unroll
    for (int i=0;i<16;i++){
      a0[i] = __builtin_amdgcn_exp2f(a0[i] - m);
      a1[i] = __builtin_amdgcn_exp2f(a1[i] - m);
    }
    float rs = 0.f;
#pragma unroll
    for (int i=0;i<16;i++) rs += a0[i] + a1[i];
    rs += __shfl_xor(rs, 32);
    l += rs;

    // ---- P -> A-fragments: cvt_pk + half-exchange ----
    // acc reg r (in 32-kv half s) holds kv = s*32 + (r&3) + 8*(r>>2) + 4*hi
    // A-frag(kb) needs kv = kb*16 + hi*8 + e (e=0..7)
    unsigned int pfd[4][4];
#pragma unroll
    for (int kb=0;kb<4;kb++){
      float cc[8];
#pragma unroll
      for (int j=0;j<8;j++) cc[j] = (kb<2) ? a0[(kb&1)*8+j] : a1[(kb&1)*8+j];
      unsigned int lo0 = cvtpk(cc[0],cc[1]), lo1 = cvtpk(cc[2],cc[3]);
      unsigned int h0  = cvtpk(cc[4],cc[5]), h1  = cvtpk(cc[6],cc[7]);
      unsigned int sl0 = (unsigned int)__shfl_xor((int)lo0, 32);
      unsigned int sl1 = (unsigned int)__shfl_xor((int)lo1, 32);
      unsigned int sh0 = (unsigned int)__shfl_xor((int)h0, 32);
      unsigned int sh1 = (unsigned int)__shfl_xor((int)h1, 32);
      pfd[kb][0] = hi ? sh0 : lo0;
      pfd[kb][1] = hi ? sh1 : lo1;
      pfd[kb][2] = hi ? h0  : sl0;
      pfd[kb][3] = hi ? h1  : sl1;
    }

    // ---- PV: O[q][d] += P[q][kv] V^T[d][kv] ----
#pragma unroll
    for (int mk=0;mk<4;mk++){
      u32x4 dd = {pfd[mk][0], pfd[mk][1], pfd[mk][2], pfd[mk][3]};
      s16x8 pa = __builtin_bit_cast(s16x8, dd);
      o0 = MFMA32(pa, vf0[mk], o0);
      o1 = MFMA32(pa, vf1[mk], o1);
    }
  }

  // ---- epilogue ----
  l_tab[wid][col] = 1.0f / l;
  const int b = bh >> 4, h = bh & 15;
#pragma unroll
  for (int r=0;r<16;r++){
    const int qloc = (r&3) + 8*(r>>2) + 4*hi;
    const float linv = l_tab[wid][qloc];
    const int tq = q0 + qloc;
    const size_t drow = ((size_t)(b*SEQ + tq))*DIM + h*HD + col;
    ao[drow]      = f2bf(o0[r] * linv);
    ao[drow + 32] = f2bf(o1[r] * linv);
  }
}

extern "C" void kernel_launch(void* const* d_in, const int* in_sizes, int n_in,
                              void* d_out, int out_size, void* d_ws, size_t ws_size,
                              hipStream_t stream){
  const float* x     = (const float*)d_in[0];
  const float* Wqkv  = (const float*)d_in[1];
  const float* bqkv  = (const float*)d_in[2];
  const float* Wproj = (const float*)d_in[3];
  const float* bproj = (const float*)d_in[4];
  float* out = (float*)d_out;

  char* ws = (char*)d_ws;
  size_t off = 0;
  auto alloc = [&](size_t bytes)->char*{
    char* p = ws + off; off += (bytes + 255) & ~(size_t)255; return p;
  };
  unsigned short* xhi    = (unsigned short*)alloc((size_t)NT*DIM*2);
  unsigned short* xlo    = (unsigned short*)alloc((size_t)NT*DIM*2);
  unsigned short* wqT_hi = (unsigned short*)alloc((size_t)N3*DIM*2);
  unsigned short* wqT_lo = (unsigned short*)alloc((size_t)N3*DIM*2);
  unsigned short* wpT_hi = (unsigned short*)alloc((size_t)DIM*DIM*2);
  unsigned short* wpT_lo = (unsigned short*)alloc((size_t)DIM*DIM*2);
  unsigned short* q_bf   = (unsigned short*)alloc((size_t)NT*DIM*2);
  unsigned short* k_bf   = (unsigned short*)alloc((size_t)NT*DIM*2);
  unsigned short* vT_bf  = (unsigned short*)alloc((size_t)NT*DIM*2);
  unsigned short* ao_bf  = (unsigned short*)alloc((size_t)NT*DIM*2);

  k_split<<<(NT*DIM/4)/256, 256, 0, stream>>>(x, xhi, xlo, NT*DIM/4);
  k_splitT<<<dim3(N3/32, DIM/32), dim3(32,8), 0, stream>>>(Wqkv, wqT_hi, wqT_lo, DIM, N3);
  k_splitT<<<dim3(DIM/32, DIM/32), dim3(32,8), 0, stream>>>(Wproj, wpT_hi, wpT_lo, DIM, DIM);
  k_gemm<0,1><<<dim3(N3/128, NT/128), 256, 0, stream>>>(xhi, xlo, wqT_hi, wqT_lo, bqkv,
                                                        q_bf, k_bf, vT_bf, nullptr);
  k_attn<<<dim3(512), 256, 0, stream>>>(q_bf, k_bf, vT_bf, ao_bf);
  k_gemm<1,0><<<dim3(DIM/128, NT/128), 256, 0, stream>>>(ao_bf, nullptr, wpT_hi, nullptr, bproj,
                                                         nullptr, nullptr, nullptr, out);
}

// Round 4
// 347.617 us; speedup vs baseline: 1.5346x; 1.5346x over previous
//
#include <hip/hip_runtime.h>
#include <hip/hip_bf16.h>
#include <stdint.h>

#define SEQ   2048
#define BATCH 2
#define DIM   1024
#define NHEAD 16
#define HD    64
#define NT    (BATCH*SEQ)   // 4096 tokens
#define N3    (3*DIM)       // 3072
#define QSCALE 0.180336881f // 0.125 * log2(e)

typedef __attribute__((ext_vector_type(4)))  float f32x4;
typedef __attribute__((ext_vector_type(16))) float f32x16;
typedef __attribute__((ext_vector_type(8)))  short s16x8;
typedef __attribute__((ext_vector_type(4)))  unsigned short u16x4;
typedef __attribute__((ext_vector_type(4)))  unsigned int u32x4;

__device__ __forceinline__ unsigned short f2bf(float x){
  union { float f; uint32_t u; } v; v.f = x;
  return (unsigned short)((v.u + 0x7fffu + ((v.u >> 16) & 1u)) >> 16);
}
__device__ __forceinline__ float bf2f(unsigned short u){
  union { uint32_t u; float f; } v; v.u = ((uint32_t)u) << 16;
  return v.f;
}
__device__ __forceinline__ unsigned int cvtpk(float lo, float hi){
  unsigned int r;
  asm("v_cvt_pk_bf16_f32 %0, %1, %2" : "=v"(r) : "v"(lo), "v"(hi));
  return r;
}
__device__ __forceinline__ void gload16(const void* g, void* l){
  __builtin_amdgcn_global_load_lds((const __attribute__((address_space(1))) void*)g,
                                   (__attribute__((address_space(3))) void*)l, 16, 0, 0);
}
__device__ __forceinline__ f32x16 zero16(){
  f32x16 z;
#pragma unroll
  for (int i=0;i<16;i++) z[i]=0.f;
  return z;
}
#define MFMA(a,b,c)   __builtin_amdgcn_mfma_f32_16x16x32_bf16((a),(b),(c),0,0,0)
#define MFMA32(a,b,c) __builtin_amdgcn_mfma_f32_32x32x16_bf16((a),(b),(c),0,0,0)

// ---------------- RoPE cos/sin table: cs[t*32+i] = (cos, sin) ----------------
__global__ __launch_bounds__(256) void k_ropetab(float2* __restrict__ cs){
  const int idx = blockIdx.x*256 + threadIdx.x;   // 65536 entries
  const int t = idx >> 5, i = idx & 31;
  const float ang = (float)t * exp2f((float)i * -0.41524101186f); // 10000^(-i/32)
  float sn, c; sincosf(ang, &sn, &c);
  cs[idx] = make_float2(c, sn);
}

// ---------------- split fp32 -> bf16 hi/lo ----------------
__global__ __launch_bounds__(256) void k_split(const float* __restrict__ in,
                                               unsigned short* __restrict__ hi,
                                               unsigned short* __restrict__ lo, int n4){
  int i = blockIdx.x*256 + threadIdx.x;
  if (i >= n4) return;
  f32x4 v = ((const f32x4*)in)[i];
  u16x4 h, l;
#pragma unroll
  for (int e=0;e<4;e++){ unsigned short hh = f2bf(v[e]); h[e]=hh; l[e]=f2bf(v[e]-bf2f(hh)); }
  ((u16x4*)hi)[i]=h; ((u16x4*)lo)[i]=l;
}

// ---------------- transpose + split: in[R][C] -> outT[C][R] ----------------
__global__ void k_splitT(const float* __restrict__ in,
                         unsigned short* __restrict__ hiT,
                         unsigned short* __restrict__ loT, int R, int C){
  __shared__ float t[32][33];
  int c0 = blockIdx.x*32, r0 = blockIdx.y*32;
  int tx = threadIdx.x, ty = threadIdx.y;
#pragma unroll
  for (int j=0;j<32;j+=8) t[ty+j][tx] = in[(size_t)(r0+ty+j)*C + c0+tx];
  __syncthreads();
#pragma unroll
  for (int j=0;j<32;j+=8){
    float v = t[tx][ty+j];
    unsigned short hh = f2bf(v);
    size_t o = (size_t)(c0+ty+j)*R + r0+tx;
    hiT[o]=hh; loT[o]=f2bf(v-bf2f(hh));
  }
}

// ---------------- transpose V: [bh][t][d] -> [bh][d][t] ----------------
__global__ __launch_bounds__(256) void k_transV(const unsigned short* __restrict__ v,
                                                unsigned short* __restrict__ vT){
  __shared__ unsigned short t[64][65];
  const int bh = blockIdx.y, t0 = blockIdx.x*64;
  const int tid = threadIdx.x;
  const size_t base = (size_t)bh*SEQ*HD;
  const int r = tid>>3, c = (tid&7)*8;
#pragma unroll
  for (int it=0; it<2; ++it){
    const int row = it*32 + r;
    s16x8 val = *(const s16x8*)(v + base + (size_t)(t0+row)*HD + c);
#pragma unroll
    for (int e=0;e<8;e++) t[row][c+e] = (unsigned short)val[e];
  }
  __syncthreads();
#pragma unroll
  for (int it=0; it<2; ++it){
    const int drow = it*32 + r;
    s16x8 o;
#pragma unroll
    for (int e=0;e<8;e++) o[e] = (short)t[c+e][drow];
    *(s16x8*)(vT + base + (size_t)drow*SEQ + t0 + c) = o;
  }
}

// ---------------- bf16 GEMM: C[M,N] = A[M,K] * B^T[N,K] + bias ----------------
// SPLIT=1: 3-MFMA split-bf16 (hi/lo). SPLIT=0: plain bf16.
// EPI==0: N=3072, epilogue = bias + RoPE via table (q scaled), scatter q,k,v [bh][t][d]
// EPI==1: N=1024, epilogue = bias, write fp32 out
template<int EPI, int SPLIT>
__global__ __launch_bounds__(256) void k_gemm(
    const unsigned short* __restrict__ Ahi, const unsigned short* __restrict__ Alo,
    const unsigned short* __restrict__ Bhi, const unsigned short* __restrict__ Blo,
    const float* __restrict__ bias, const float2* __restrict__ cstab,
    unsigned short* __restrict__ qb, unsigned short* __restrict__ kbp,
    unsigned short* __restrict__ vbp, float* __restrict__ outp){
  __shared__ unsigned short sA[SPLIT+1][128*32];
  __shared__ unsigned short sB[SPLIT+1][128*32];
  const int tid = threadIdx.x;
  const int w = tid>>6, lane = tid&63;
  const int lr = lane&15, lk = lane>>4;
  const int wm = (w>>1)*64, wn = (w&1)*64;
  const int m0 = blockIdx.y*128, n0 = blockIdx.x*128;

  f32x4 acc[4][4];
#pragma unroll
  for (int m=0;m<4;m++)
#pragma unroll
    for (int n=0;n<4;n++) acc[m][n] = (f32x4){0.f,0.f,0.f,0.f};

  const int srow  = lane>>2;       // row within 16-row chunk
  const int sbyte = (lane&3)*16;   // byte col within 64B row

  for (int kt=0; kt<1024/32; ++kt){
    const int k0 = kt*32;
#pragma unroll
    for (int cc=0; cc<2; ++cc){
      const int chunk = w*2+cc;
      const int row = chunk*16 + srow;
      const size_t aoff = ((size_t)(m0+row)*1024 + k0)*2 + sbyte;
      const size_t boff = ((size_t)(n0+row)*1024 + k0)*2 + sbyte;
      gload16((const char*)Ahi + aoff, (char*)(&sA[0][0]) + chunk*1024);
      gload16((const char*)Bhi + boff, (char*)(&sB[0][0]) + chunk*1024);
      if constexpr (SPLIT){
        gload16((const char*)Alo + aoff, (char*)(&sA[1][0]) + chunk*1024);
        gload16((const char*)Blo + boff, (char*)(&sB[1][0]) + chunk*1024);
      }
    }
    __syncthreads();

    s16x8 ah[4], al[4], bh[4], bl[4];
#pragma unroll
    for (int m=0;m<4;m++){
      const int off = (wm + m*16 + lr)*64 + lk*16;
      ah[m] = *(const s16x8*)((const char*)(&sA[0][0]) + off);
      if constexpr (SPLIT) al[m] = *(const s16x8*)((const char*)(&sA[1][0]) + off);
    }
#pragma unroll
    for (int n=0;n<4;n++){
      const int off = (wn + n*16 + lr)*64 + lk*16;
      bh[n] = *(const s16x8*)((const char*)(&sB[0][0]) + off);
      if constexpr (SPLIT) bl[n] = *(const s16x8*)((const char*)(&sB[1][0]) + off);
    }
#pragma unroll
    for (int m=0;m<4;m++)
#pragma unroll
      for (int n=0;n<4;n++){
        acc[m][n] = MFMA(ah[m], bh[n], acc[m][n]);
        if constexpr (SPLIT){
          acc[m][n] = MFMA(ah[m], bl[n], acc[m][n]);
          acc[m][n] = MFMA(al[m], bh[n], acc[m][n]);
        }
      }
    __syncthreads();
  }

  // epilogue
#pragma unroll
  for (int m=0;m<4;m++)
#pragma unroll
    for (int n=0;n<4;n++)
#pragma unroll
      for (int r=0;r<4;r++){
        const int gm = m0 + wm + m*16 + lk*4 + r;
        const int gn = n0 + wn + n*16 + lr;
        float val = acc[m][n][r] + bias[gn];
        if (EPI == 0){
          const int three = gn>>10, rem = gn&1023, h = rem>>6, d = rem&63;
          const int b = gm>>11, t = gm&2047;
          const float partner = __shfl_xor(val, 1);
          const size_t dst = ((size_t)(b*NHEAD + h))*SEQ*HD + (size_t)t*HD + d;
          if (three < 2){
            const float2 cs = cstab[t*32 + (d>>1)];
            float o;
            if (d & 1) o = partner*cs.y + val*cs.x;   // im' = re*sin + im*cos
            else       o = val*cs.x - partner*cs.y;   // re' = re*cos - im*sin
            if (three==0) qb[dst] = f2bf(o*QSCALE);
            else          kbp[dst] = f2bf(o);
          } else {
            vbp[dst] = f2bf(val);
          }
        } else {
          outp[(size_t)gm*DIM + gn] = val;
        }
      }
}

// ---------------- flash attention: 32x32 MFMA, swapped QK^T, in-reg softmax ----------------
__global__ __launch_bounds__(256) void k_attn(const unsigned short* __restrict__ qb,
                                              const unsigned short* __restrict__ kb,
                                              const unsigned short* __restrict__ vTb,
                                              unsigned short* __restrict__ ao){
  __shared__ float l_tab[4][32];
  const int flat = blockIdx.x;
  const int wi = (flat & 7)*64 + (flat >> 3);   // XCD swizzle (512 blocks)
  const int bh = wi >> 4, qt = wi & 15;
  const int wid = threadIdx.x >> 6, lane = threadIdx.x & 63;
  const int col = lane & 31, hi = lane >> 5;
  const size_t base = (size_t)bh*SEQ*HD;
  const int q0 = qt*128 + wid*32;

  s16x8 qf[4];
  {
    const unsigned short* qp = qb + base + (size_t)(q0+col)*HD + hi*8;
#pragma unroll
    for (int hb=0;hb<4;hb++) qf[hb] = *(const s16x8*)(qp + hb*16);
  }

  f32x16 o0 = zero16(), o1 = zero16();
  float m = -INFINITY, l = 0.f;

  for (int kv0 = 0; kv0 < SEQ; kv0 += 64){
    s16x8 kf0[4], kf1[4];
    {
      const unsigned short* kp0 = kb + base + (size_t)(kv0+col)*HD + hi*8;
      const unsigned short* kp1 = kp0 + 32*HD;
#pragma unroll
      for (int hb=0;hb<4;hb++){
        kf0[hb] = *(const s16x8*)(kp0 + hb*16);
        kf1[hb] = *(const s16x8*)(kp1 + hb*16);
      }
    }
    f32x16 a0 = zero16(), a1 = zero16();
#pragma unroll
    for (int hb=0;hb<4;hb++){
      a0 = MFMA32(kf0[hb], qf[hb], a0);
      a1 = MFMA32(kf1[hb], qf[hb], a1);
    }

    s16x8 vf0[4], vf1[4];
    {
      const unsigned short* vp0 = vTb + base + (size_t)col*SEQ + kv0 + hi*8;
      const unsigned short* vp1 = vp0 + (size_t)32*SEQ;
#pragma unroll
      for (int mk=0;mk<4;mk++){
        vf0[mk] = *(const s16x8*)(vp0 + mk*16);
        vf1[mk] = *(const s16x8*)(vp1 + mk*16);
      }
    }

    float pm = a0[0];
#pragma unroll
    for (int i=1;i<16;i++) pm = fmaxf(pm, a0[i]);
#pragma unroll
    for (int i=0;i<16;i++) pm = fmaxf(pm, a1[i]);
    pm = fmaxf(pm, __shfl_xor(pm, 32));

    if (!__all(pm - m <= 8.0f)){   // T13 defer-max
      const float mn = fmaxf(m, pm);
      const float al = __builtin_amdgcn_exp2f(m - mn);
      l *= al;
#pragma unroll
      for (int i=0;i<16;i++){ o0[i] *= al; o1[i] *= al; }
      m = mn;
    }
#pragma unroll
    for (int i=0;i<16;i++){
      a0[i] = __builtin_amdgcn_exp2f(a0[i] - m);
      a1[i] = __builtin_amdgcn_exp2f(a1[i] - m);
    }
    float rs = 0.f;
#pragma unroll
    for (int i=0;i<16;i++) rs += a0[i] + a1[i];
    rs += __shfl_xor(rs, 32);
    l += rs;

    unsigned int pfd[4][4];
#pragma unroll
    for (int kb=0;kb<4;kb++){
      float cc[8];
#pragma unroll
      for (int j=0;j<8;j++) cc[j] = (kb<2) ? a0[(kb&1)*8+j] : a1[(kb&1)*8+j];
      unsigned int lo0 = cvtpk(cc[0],cc[1]), lo1 = cvtpk(cc[2],cc[3]);
      unsigned int h0  = cvtpk(cc[4],cc[5]), h1  = cvtpk(cc[6],cc[7]);
      unsigned int sl0 = (unsigned int)__shfl_xor((int)lo0, 32);
      unsigned int sl1 = (unsigned int)__shfl_xor((int)lo1, 32);
      unsigned int sh0 = (unsigned int)__shfl_xor((int)h0, 32);
      unsigned int sh1 = (unsigned int)__shfl_xor((int)h1, 32);
      pfd[kb][0] = hi ? sh0 : lo0;
      pfd[kb][1] = hi ? sh1 : lo1;
      pfd[kb][2] = hi ? h0  : sl0;
      pfd[kb][3] = hi ? h1  : sl1;
    }

#pragma unroll
    for (int mk=0;mk<4;mk++){
      u32x4 dd = {pfd[mk][0], pfd[mk][1], pfd[mk][2], pfd[mk][3]};
      s16x8 pa = __builtin_bit_cast(s16x8, dd);
      o0 = MFMA32(pa, vf0[mk], o0);
      o1 = MFMA32(pa, vf1[mk], o1);
    }
  }

  l_tab[wid][col] = 1.0f / l;
  const int b = bh >> 4, h = bh & 15;
#pragma unroll
  for (int r=0;r<16;r++){
    const int qloc = (r&3) + 8*(r>>2) + 4*hi;
    const float linv = l_tab[wid][qloc];
    const int tq = q0 + qloc;
    const size_t drow = ((size_t)(b*SEQ + tq))*DIM + h*HD + col;
    ao[drow]      = f2bf(o0[r] * linv);
    ao[drow + 32] = f2bf(o1[r] * linv);
  }
}

extern "C" void kernel_launch(void* const* d_in, const int* in_sizes, int n_in,
                              void* d_out, int out_size, void* d_ws, size_t ws_size,
                              hipStream_t stream){
  const float* x     = (const float*)d_in[0];
  const float* Wqkv  = (const float*)d_in[1];
  const float* bqkv  = (const float*)d_in[2];
  const float* Wproj = (const float*)d_in[3];
  const float* bproj = (const float*)d_in[4];
  float* out = (float*)d_out;

  char* ws = (char*)d_ws;
  size_t off = 0;
  auto alloc = [&](size_t bytes)->char*{
    char* p = ws + off; off += (bytes + 255) & ~(size_t)255; return p;
  };
  unsigned short* xhi    = (unsigned short*)alloc((size_t)NT*DIM*2);
  unsigned short* xlo    = (unsigned short*)alloc((size_t)NT*DIM*2);
  unsigned short* wqT_hi = (unsigned short*)alloc((size_t)N3*DIM*2);
  unsigned short* wqT_lo = (unsigned short*)alloc((size_t)N3*DIM*2);
  unsigned short* wpT_hi = (unsigned short*)alloc((size_t)DIM*DIM*2);
  unsigned short* wpT_lo = (unsigned short*)alloc((size_t)DIM*DIM*2);
  unsigned short* q_bf   = (unsigned short*)alloc((size_t)NT*DIM*2);
  unsigned short* k_bf   = (unsigned short*)alloc((size_t)NT*DIM*2);
  unsigned short* v_bf   = (unsigned short*)alloc((size_t)NT*DIM*2);
  unsigned short* vT_bf  = (unsigned short*)alloc((size_t)NT*DIM*2);
  unsigned short* ao_bf  = (unsigned short*)alloc((size_t)NT*DIM*2);
  float2*         cstab  = (float2*)alloc((size_t)SEQ*32*sizeof(float2));

  k_ropetab<<<SEQ*32/256, 256, 0, stream>>>(cstab);
  k_split<<<(NT*DIM/4)/256, 256, 0, stream>>>(x, xhi, xlo, NT*DIM/4);
  k_splitT<<<dim3(N3/32, DIM/32), dim3(32,8), 0, stream>>>(Wqkv, wqT_hi, wqT_lo, DIM, N3);
  k_splitT<<<dim3(DIM/32, DIM/32), dim3(32,8), 0, stream>>>(Wproj, wpT_hi, wpT_lo, DIM, DIM);
  k_gemm<0,1><<<dim3(N3/128, NT/128), 256, 0, stream>>>(xhi, xlo, wqT_hi, wqT_lo, bqkv, cstab,
                                                        q_bf, k_bf, v_bf, nullptr);
  k_transV<<<dim3(SEQ/64, BATCH*NHEAD), 256, 0, stream>>>(v_bf, vT_bf);
  k_attn<<<dim3(512), 256, 0, stream>>>(q_bf, k_bf, vT_bf, ao_bf);
  k_gemm<1,0><<<dim3(DIM/128, NT/128), 256, 0, stream>>>(ao_bf, nullptr, wpT_hi, nullptr, bproj, nullptr,
                                                         nullptr, nullptr, nullptr, out);
}

// Round 6
// 344.600 us; speedup vs baseline: 1.5480x; 1.0088x over previous
//
#include <hip/hip_runtime.h>
#include <hip/hip_bf16.h>
#include <stdint.h>

#define SEQ   2048
#define BATCH 2
#define DIM   1024
#define NHEAD 16
#define HD    64
#define NT    (BATCH*SEQ)   // 4096 tokens
#define N3    (3*DIM)       // 3072
#define QSCALE 0.180336881f // 0.125 * log2(e)

typedef __attribute__((ext_vector_type(4)))  float f32x4;
typedef __attribute__((ext_vector_type(16))) float f32x16;
typedef __attribute__((ext_vector_type(8)))  short s16x8;
typedef __attribute__((ext_vector_type(4)))  unsigned short u16x4;
typedef __attribute__((ext_vector_type(4)))  unsigned int u32x4;

__device__ __forceinline__ unsigned short f2bf(float x){
  union { float f; uint32_t u; } v; v.f = x;
  return (unsigned short)((v.u + 0x7fffu + ((v.u >> 16) & 1u)) >> 16);
}
__device__ __forceinline__ float bf2f(unsigned short u){
  union { uint32_t u; float f; } v; v.u = ((uint32_t)u) << 16;
  return v.f;
}
__device__ __forceinline__ unsigned int cvtpk(float lo, float hi){
  unsigned int r;
  asm("v_cvt_pk_bf16_f32 %0, %1, %2" : "=v"(r) : "v"(lo), "v"(hi));
  return r;
}
__device__ __forceinline__ void gload16(const void* g, void* l){
  __builtin_amdgcn_global_load_lds((const __attribute__((address_space(1))) void*)g,
                                   (__attribute__((address_space(3))) void*)l, 16, 0, 0);
}
__device__ __forceinline__ f32x16 zero16(){
  f32x16 z;
#pragma unroll
  for (int i=0;i<16;i++) z[i]=0.f;
  return z;
}
#define MFMA(a,b,c)   __builtin_amdgcn_mfma_f32_16x16x32_bf16((a),(b),(c),0,0,0)
#define MFMA32(a,b,c) __builtin_amdgcn_mfma_f32_32x32x16_bf16((a),(b),(c),0,0,0)

// ---------------- RoPE cos/sin table: cs[t*32+i] = (cos, sin) ----------------
__global__ __launch_bounds__(256) void k_ropetab(float2* __restrict__ cs){
  const int idx = blockIdx.x*256 + threadIdx.x;   // 65536 entries
  const int t = idx >> 5, i = idx & 31;
  const float ang = (float)t * exp2f((float)i * -0.41524101186f); // 10000^(-i/32)
  float sn, c; sincosf(ang, &sn, &c);
  cs[idx] = make_float2(c, sn);
}

// ---------------- split fp32 -> bf16 hi/lo ----------------
__global__ __launch_bounds__(256) void k_split(const float* __restrict__ in,
                                               unsigned short* __restrict__ hi,
                                               unsigned short* __restrict__ lo, int n4){
  int i = blockIdx.x*256 + threadIdx.x;
  if (i >= n4) return;
  f32x4 v = ((const f32x4*)in)[i];
  u16x4 h, l;
#pragma unroll
  for (int e=0;e<4;e++){ unsigned short hh = f2bf(v[e]); h[e]=hh; l[e]=f2bf(v[e]-bf2f(hh)); }
  ((u16x4*)hi)[i]=h; ((u16x4*)lo)[i]=l;
}

// ---------------- transpose + split: in[R][C] f32 -> outT[C][R] bf16 hi/lo ----------------
__global__ void k_splitT(const float* __restrict__ in,
                         unsigned short* __restrict__ hiT,
                         unsigned short* __restrict__ loT, int R, int C){
  __shared__ float t[32][33];
  int c0 = blockIdx.x*32, r0 = blockIdx.y*32;
  int tx = threadIdx.x, ty = threadIdx.y;
#pragma unroll
  for (int j=0;j<32;j+=8) t[ty+j][tx] = in[(size_t)(r0+ty+j)*C + c0+tx];
  __syncthreads();
#pragma unroll
  for (int j=0;j<32;j+=8){
    float v = t[tx][ty+j];
    unsigned short hh = f2bf(v);
    size_t o = (size_t)(c0+ty+j)*R + r0+tx;
    hiT[o]=hh; loT[o]=f2bf(v-bf2f(hh));
  }
}

// ---------------- transpose + convert: in[R][C] f32 -> outT[C][R] bf16 ----------------
__global__ void k_transT(const float* __restrict__ in,
                         unsigned short* __restrict__ oT, int R, int C){
  __shared__ float t[32][33];
  int c0 = blockIdx.x*32, r0 = blockIdx.y*32;
  int tx = threadIdx.x, ty = threadIdx.y;
#pragma unroll
  for (int j=0;j<32;j+=8) t[ty+j][tx] = in[(size_t)(r0+ty+j)*C + c0+tx];
  __syncthreads();
#pragma unroll
  for (int j=0;j<32;j+=8)
    oT[(size_t)(c0+ty+j)*R + r0+tx] = f2bf(t[tx][ty+j]);
}

// ---------------- transpose V: [bh][t][d] -> [bh][d][t] ----------------
__global__ __launch_bounds__(256) void k_transV(const unsigned short* __restrict__ v,
                                                unsigned short* __restrict__ vT){
  __shared__ unsigned short t[64][65];
  const int bh = blockIdx.y, t0 = blockIdx.x*64;
  const int tid = threadIdx.x;
  const size_t base = (size_t)bh*SEQ*HD;
  const int r = tid>>3, c = (tid&7)*8;
#pragma unroll
  for (int it=0; it<2; ++it){
    const int row = it*32 + r;
    s16x8 val = *(const s16x8*)(v + base + (size_t)(t0+row)*HD + c);
#pragma unroll
    for (int e=0;e<8;e++) t[row][c+e] = (unsigned short)val[e];
  }
  __syncthreads();
#pragma unroll
  for (int it=0; it<2; ++it){
    const int drow = it*32 + r;
    s16x8 o;
#pragma unroll
    for (int e=0;e<8;e++) o[e] = (short)t[c+e][drow];
    *(s16x8*)(vT + base + (size_t)drow*SEQ + t0 + c) = o;
  }
}

// ---------------- split-bf16 QKV GEMM: C[M,3072] = A[M,1024]*B^T + bias, RoPE, scatter ----
__global__ __launch_bounds__(256) void k_gemm(
    const unsigned short* __restrict__ Ahi, const unsigned short* __restrict__ Alo,
    const unsigned short* __restrict__ Bhi, const unsigned short* __restrict__ Blo,
    const float* __restrict__ bias, const float2* __restrict__ cstab,
    unsigned short* __restrict__ qb, unsigned short* __restrict__ kbp,
    unsigned short* __restrict__ vbp){
  __shared__ unsigned short sA[2][128*32];
  __shared__ unsigned short sB[2][128*32];
  const int tid = threadIdx.x;
  const int w = tid>>6, lane = tid&63;
  const int lr = lane&15, lk = lane>>4;
  const int wm = (w>>1)*64, wn = (w&1)*64;
  const int m0 = blockIdx.y*128, n0 = blockIdx.x*128;

  f32x4 acc[4][4];
#pragma unroll
  for (int m=0;m<4;m++)
#pragma unroll
    for (int n=0;n<4;n++) acc[m][n] = (f32x4){0.f,0.f,0.f,0.f};

  const int srow  = lane>>2;       // row within 16-row chunk
  const int sbyte = (lane&3)*16;   // byte col within 64B row

  for (int kt=0; kt<1024/32; ++kt){
    const int k0 = kt*32;
#pragma unroll
    for (int cc=0; cc<2; ++cc){
      const int chunk = w*2+cc;
      const int row = chunk*16 + srow;
      const size_t aoff = ((size_t)(m0+row)*1024 + k0)*2 + sbyte;
      const size_t boff = ((size_t)(n0+row)*1024 + k0)*2 + sbyte;
      gload16((const char*)Ahi + aoff, (char*)(&sA[0][0]) + chunk*1024);
      gload16((const char*)Bhi + boff, (char*)(&sB[0][0]) + chunk*1024);
      gload16((const char*)Alo + aoff, (char*)(&sA[1][0]) + chunk*1024);
      gload16((const char*)Blo + boff, (char*)(&sB[1][0]) + chunk*1024);
    }
    __syncthreads();

    s16x8 ah[4], al[4], bh[4], bl[4];
#pragma unroll
    for (int m=0;m<4;m++){
      const int off = (wm + m*16 + lr)*64 + lk*16;
      ah[m] = *(const s16x8*)((const char*)(&sA[0][0]) + off);
      al[m] = *(const s16x8*)((const char*)(&sA[1][0]) + off);
    }
#pragma unroll
    for (int n=0;n<4;n++){
      const int off = (wn + n*16 + lr)*64 + lk*16;
      bh[n] = *(const s16x8*)((const char*)(&sB[0][0]) + off);
      bl[n] = *(const s16x8*)((const char*)(&sB[1][0]) + off);
    }
#pragma unroll
    for (int m=0;m<4;m++)
#pragma unroll
      for (int n=0;n<4;n++){
        acc[m][n] = MFMA(ah[m], bh[n], acc[m][n]);
        acc[m][n] = MFMA(ah[m], bl[n], acc[m][n]);
        acc[m][n] = MFMA(al[m], bh[n], acc[m][n]);
      }
    __syncthreads();
  }

#pragma unroll
  for (int m=0;m<4;m++)
#pragma unroll
    for (int n=0;n<4;n++)
#pragma unroll
      for (int r=0;r<4;r++){
        const int gm = m0 + wm + m*16 + lk*4 + r;
        const int gn = n0 + wn + n*16 + lr;
        float val = acc[m][n][r] + bias[gn];
        const int three = gn>>10, rem = gn&1023, h = rem>>6, d = rem&63;
        const int b = gm>>11, t = gm&2047;
        const float partner = __shfl_xor(val, 1);
        const size_t dst = ((size_t)(b*NHEAD + h))*SEQ*HD + (size_t)t*HD + d;
        if (three < 2){
          const float2 cs = cstab[t*32 + (d>>1)];
          float o;
          if (d & 1) o = partner*cs.y + val*cs.x;   // im' = re*sin + im*cos
          else       o = val*cs.x - partner*cs.y;   // re' = re*cos - im*sin
          if (three==0) qb[dst] = f2bf(o*QSCALE);
          else          kbp[dst] = f2bf(o);
        } else {
          vbp[dst] = f2bf(val);
        }
      }
}

// ---------------- proj GEMM: out[4096,1024] = A[4096,1024]*B^T + bias (fp32 out) ----------------
// BM=128, BN=64 -> grid (16, 32) = 512 blocks (2/CU)
__global__ __launch_bounds__(256) void k_gemmP(
    const unsigned short* __restrict__ A, const unsigned short* __restrict__ B,
    const float* __restrict__ bias, float* __restrict__ outp){
  __shared__ unsigned short sA[128*32];
  __shared__ unsigned short sB[64*32];
  const int tid = threadIdx.x;
  const int w = tid>>6, lane = tid&63;
  const int lr = lane&15, lk = lane>>4;
  const int m0 = blockIdx.y*128, n0 = blockIdx.x*64;

  f32x4 acc[2][4];
#pragma unroll
  for (int m=0;m<2;m++)
#pragma unroll
    for (int n=0;n<4;n++) acc[m][n] = (f32x4){0.f,0.f,0.f,0.f};

  const int srow  = lane>>2;
  const int sbyte = (lane&3)*16;

  for (int kt=0; kt<1024/32; ++kt){
    const int k0 = kt*32;
#pragma unroll
    for (int cc=0; cc<2; ++cc){
      const int chunk = w*2+cc;
      const int row = chunk*16 + srow;
      gload16((const char*)A + ((size_t)(m0+row)*1024 + k0)*2 + sbyte,
              (char*)sA + chunk*1024);
    }
    { // B: 4 chunks of 16 rows, wave w stages chunk w
      const int row = w*16 + srow;
      gload16((const char*)B + ((size_t)(n0+row)*1024 + k0)*2 + sbyte,
              (char*)sB + w*1024);
    }
    __syncthreads();

    s16x8 ah[2], bh[4];
#pragma unroll
    for (int m=0;m<2;m++)
      ah[m] = *(const s16x8*)((const char*)sA + (w*32 + m*16 + lr)*64 + lk*16);
#pragma unroll
    for (int n=0;n<4;n++)
      bh[n] = *(const s16x8*)((const char*)sB + (n*16 + lr)*64 + lk*16);
#pragma unroll
    for (int m=0;m<2;m++)
#pragma unroll
      for (int n=0;n<4;n++)
        acc[m][n] = MFMA(ah[m], bh[n], acc[m][n]);
    __syncthreads();
  }

#pragma unroll
  for (int m=0;m<2;m++)
#pragma unroll
    for (int n=0;n<4;n++)
#pragma unroll
      for (int r=0;r<4;r++){
        const int gm = m0 + w*32 + m*16 + lk*4 + r;
        const int gn = n0 + n*16 + lr;
        outp[(size_t)gm*DIM + gn] = acc[m][n][r] + bias[gn];
      }
}

// ---------------- flash attention: 32x32 MFMA, swapped QK^T, in-reg softmax ----------------
__global__ __launch_bounds__(256) void k_attn(const unsigned short* __restrict__ qb,
                                              const unsigned short* __restrict__ kb,
                                              const unsigned short* __restrict__ vTb,
                                              unsigned short* __restrict__ ao){
  __shared__ float l_tab[4][32];
  const int flat = blockIdx.x;
  const int wi = (flat & 7)*64 + (flat >> 3);   // XCD swizzle (512 blocks)
  const int bh = wi >> 4, qt = wi & 15;
  const int wid = threadIdx.x >> 6, lane = threadIdx.x & 63;
  const int col = lane & 31, hi = lane >> 5;
  const size_t base = (size_t)bh*SEQ*HD;
  const int q0 = qt*128 + wid*32;

  s16x8 qf[4];
  {
    const unsigned short* qp = qb + base + (size_t)(q0+col)*HD + hi*8;
#pragma unroll
    for (int hb=0;hb<4;hb++) qf[hb] = *(const s16x8*)(qp + hb*16);
  }

  f32x16 o0 = zero16(), o1 = zero16();
  float m = -INFINITY, l = 0.f;

  for (int kv0 = 0; kv0 < SEQ; kv0 += 64){
    s16x8 kf0[4], kf1[4];
    {
      const unsigned short* kp0 = kb + base + (size_t)(kv0+col)*HD + hi*8;
      const unsigned short* kp1 = kp0 + 32*HD;
#pragma unroll
      for (int hb=0;hb<4;hb++){
        kf0[hb] = *(const s16x8*)(kp0 + hb*16);
        kf1[hb] = *(const s16x8*)(kp1 + hb*16);
      }
    }
    f32x16 a0 = zero16(), a1 = zero16();
    __builtin_amdgcn_s_setprio(1);
#pragma unroll
    for (int hb=0;hb<4;hb++){
      a0 = MFMA32(kf0[hb], qf[hb], a0);
      a1 = MFMA32(kf1[hb], qf[hb], a1);
    }
    __builtin_amdgcn_s_setprio(0);

    s16x8 vf0[4], vf1[4];
    {
      const unsigned short* vp0 = vTb + base + (size_t)col*SEQ + kv0 + hi*8;
      const unsigned short* vp1 = vp0 + (size_t)32*SEQ;
#pragma unroll
      for (int mk=0;mk<4;mk++){
        vf0[mk] = *(const s16x8*)(vp0 + mk*16);
        vf1[mk] = *(const s16x8*)(vp1 + mk*16);
      }
    }

    // in-register online softmax (log2 domain; scale folded into Q)
    float pm = a0[0];
#pragma unroll
    for (int i=1;i<16;i++) pm = fmaxf(pm, a0[i]);
#pragma unroll
    for (int i=0;i<16;i++) pm = fmaxf(pm, a1[i]);
    pm = fmaxf(pm, __shfl_xor(pm, 32));

    if (!__all(pm - m <= 8.0f)){   // T13 defer-max
      const float mn = fmaxf(m, pm);
      const float al = __builtin_amdgcn_exp2f(m - mn);
      l *= al;
#pragma unroll
      for (int i=0;i<16;i++){ o0[i] *= al; o1[i] *= al; }
      m = mn;
    }
#pragma unroll
    for (int i=0;i<16;i++){
      a0[i] = __builtin_amdgcn_exp2f(a0[i] - m);
      a1[i] = __builtin_amdgcn_exp2f(a1[i] - m);
    }
    float rs = 0.f;
#pragma unroll
    for (int i=0;i<16;i++) rs += a0[i] + a1[i];
    rs += __shfl_xor(rs, 32);
    l += rs;

    // P -> A-fragments: cvt_pk + shfl_xor(32) half-exchange (round-4 proven form)
    unsigned int pfd[4][4];
#pragma unroll
    for (int kb=0;kb<4;kb++){
      float cc[8];
#pragma unroll
      for (int j=0;j<8;j++) cc[j] = (kb<2) ? a0[(kb&1)*8+j] : a1[(kb&1)*8+j];
      unsigned int lo0 = cvtpk(cc[0],cc[1]), lo1 = cvtpk(cc[2],cc[3]);
      unsigned int h0  = cvtpk(cc[4],cc[5]), h1  = cvtpk(cc[6],cc[7]);
      unsigned int sl0 = (unsigned int)__shfl_xor((int)lo0, 32);
      unsigned int sl1 = (unsigned int)__shfl_xor((int)lo1, 32);
      unsigned int sh0 = (unsigned int)__shfl_xor((int)h0, 32);
      unsigned int sh1 = (unsigned int)__shfl_xor((int)h1, 32);
      pfd[kb][0] = hi ? sh0 : lo0;
      pfd[kb][1] = hi ? sh1 : lo1;
      pfd[kb][2] = hi ? h0  : sl0;
      pfd[kb][3] = hi ? h1  : sl1;
    }

    __builtin_amdgcn_s_setprio(1);
#pragma unroll
    for (int mk=0;mk<4;mk++){
      u32x4 dd = {pfd[mk][0], pfd[mk][1], pfd[mk][2], pfd[mk][3]};
      s16x8 pa = __builtin_bit_cast(s16x8, dd);
      o0 = MFMA32(pa, vf0[mk], o0);
      o1 = MFMA32(pa, vf1[mk], o1);
    }
    __builtin_amdgcn_s_setprio(0);
  }

  l_tab[wid][col] = 1.0f / l;
  const int b = bh >> 4, h = bh & 15;
#pragma unroll
  for (int r=0;r<16;r++){
    const int qloc = (r&3) + 8*(r>>2) + 4*hi;
    const float linv = l_tab[wid][qloc];
    const int tq = q0 + qloc;
    const size_t drow = ((size_t)(b*SEQ + tq))*DIM + h*HD + col;
    ao[drow]      = f2bf(o0[r] * linv);
    ao[drow + 32] = f2bf(o1[r] * linv);
  }
}

extern "C" void kernel_launch(void* const* d_in, const int* in_sizes, int n_in,
                              void* d_out, int out_size, void* d_ws, size_t ws_size,
                              hipStream_t stream){
  const float* x     = (const float*)d_in[0];
  const float* Wqkv  = (const float*)d_in[1];
  const float* bqkv  = (const float*)d_in[2];
  const float* Wproj = (const float*)d_in[3];
  const float* bproj = (const float*)d_in[4];
  float* out = (float*)d_out;

  char* ws = (char*)d_ws;
  size_t off = 0;
  auto alloc = [&](size_t bytes)->char*{
    char* p = ws + off; off += (bytes + 255) & ~(size_t)255; return p;
  };
  unsigned short* xhi    = (unsigned short*)alloc((size_t)NT*DIM*2);
  unsigned short* xlo    = (unsigned short*)alloc((size_t)NT*DIM*2);
  unsigned short* wqT_hi = (unsigned short*)alloc((size_t)N3*DIM*2);
  unsigned short* wqT_lo = (unsigned short*)alloc((size_t)N3*DIM*2);
  unsigned short* wpT    = (unsigned short*)alloc((size_t)DIM*DIM*2);
  unsigned short* q_bf   = (unsigned short*)alloc((size_t)NT*DIM*2);
  unsigned short* k_bf   = (unsigned short*)alloc((size_t)NT*DIM*2);
  unsigned short* v_bf   = (unsigned short*)alloc((size_t)NT*DIM*2);
  unsigned short* vT_bf  = (unsigned short*)alloc((size_t)NT*DIM*2);
  unsigned short* ao_bf  = (unsigned short*)alloc((size_t)NT*DIM*2);
  float2*         cstab  = (float2*)alloc((size_t)SEQ*32*sizeof(float2));

  k_ropetab<<<SEQ*32/256, 256, 0, stream>>>(cstab);
  k_split<<<(NT*DIM/4)/256, 256, 0, stream>>>(x, xhi, xlo, NT*DIM/4);
  k_splitT<<<dim3(N3/32, DIM/32), dim3(32,8), 0, stream>>>(Wqkv, wqT_hi, wqT_lo, DIM, N3);
  k_transT<<<dim3(DIM/32, DIM/32), dim3(32,8), 0, stream>>>(Wproj, wpT, DIM, DIM);
  k_gemm<<<dim3(N3/128, NT/128), 256, 0, stream>>>(xhi, xlo, wqT_hi, wqT_lo, bqkv, cstab,
                                                   q_bf, k_bf, v_bf);
  k_transV<<<dim3(SEQ/64, BATCH*NHEAD), 256, 0, stream>>>(v_bf, vT_bf);
  k_attn<<<dim3(512), 256, 0, stream>>>(q_bf, k_bf, vT_bf, ao_bf);
  k_gemmP<<<dim3(DIM/64, NT/128), 256, 0, stream>>>(ao_bf, wpT, bproj, out);
}

// Round 7
// 277.881 us; speedup vs baseline: 1.9197x; 1.2401x over previous
//
#include <hip/hip_runtime.h>
#include <hip/hip_bf16.h>
#include <stdint.h>

#define SEQ   2048
#define BATCH 2
#define DIM   1024
#define NHEAD 16
#define HD    64
#define NT    (BATCH*SEQ)   // 4096 tokens
#define N3    (3*DIM)       // 3072
#define QSCALE 0.180336881f // 0.125 * log2(e)

typedef __attribute__((ext_vector_type(4)))  float f32x4;
typedef __attribute__((ext_vector_type(16))) float f32x16;
typedef __attribute__((ext_vector_type(8)))  short s16x8;
typedef __attribute__((ext_vector_type(4)))  unsigned short u16x4;
typedef __attribute__((ext_vector_type(4)))  unsigned int u32x4;

__device__ __forceinline__ unsigned short f2bf(float x){
  union { float f; uint32_t u; } v; v.f = x;
  return (unsigned short)((v.u + 0x7fffu + ((v.u >> 16) & 1u)) >> 16);
}
__device__ __forceinline__ unsigned int cvtpk(float lo, float hi){
  unsigned int r;
  asm("v_cvt_pk_bf16_f32 %0, %1, %2" : "=v"(r) : "v"(lo), "v"(hi));
  return r;
}
__device__ __forceinline__ void gload16(const void* g, void* l){
  __builtin_amdgcn_global_load_lds((const __attribute__((address_space(1))) void*)g,
                                   (__attribute__((address_space(3))) void*)l, 16, 0, 0);
}
__device__ __forceinline__ f32x16 zero16(){
  f32x16 z;
#pragma unroll
  for (int i=0;i<16;i++) z[i]=0.f;
  return z;
}
#define MFMA(a,b,c)   __builtin_amdgcn_mfma_f32_16x16x32_bf16((a),(b),(c),0,0,0)
#define MFMA32(a,b,c) __builtin_amdgcn_mfma_f32_32x32x16_bf16((a),(b),(c),0,0,0)

// ---------------- RoPE cos/sin table: cs[t*32+i] = (cos, sin) ----------------
__global__ __launch_bounds__(256) void k_ropetab(float2* __restrict__ cs){
  const int idx = blockIdx.x*256 + threadIdx.x;   // 65536 entries
  const int t = idx >> 5, i = idx & 31;
  const float ang = (float)t * exp2f((float)i * -0.41524101186f); // 10000^(-i/32)
  float sn, c; sincosf(ang, &sn, &c);
  cs[idx] = make_float2(c, sn);
}

// ---------------- convert fp32 -> bf16 ----------------
__global__ __launch_bounds__(256) void k_tobf(const float* __restrict__ in,
                                              unsigned short* __restrict__ o, int n4){
  int i = blockIdx.x*256 + threadIdx.x;
  if (i >= n4) return;
  f32x4 v = ((const f32x4*)in)[i];
  u16x4 h;
#pragma unroll
  for (int e=0;e<4;e++) h[e] = f2bf(v[e]);
  ((u16x4*)o)[i] = h;
}

// ---------------- transpose + convert: in[R][C] f32 -> outT[C][R] bf16 ----------------
__global__ void k_transT(const float* __restrict__ in,
                         unsigned short* __restrict__ oT, int R, int C){
  __shared__ float t[32][33];
  int c0 = blockIdx.x*32, r0 = blockIdx.y*32;
  int tx = threadIdx.x, ty = threadIdx.y;
#pragma unroll
  for (int j=0;j<32;j+=8) t[ty+j][tx] = in[(size_t)(r0+ty+j)*C + c0+tx];
  __syncthreads();
#pragma unroll
  for (int j=0;j<32;j+=8)
    oT[(size_t)(c0+ty+j)*R + r0+tx] = f2bf(t[tx][ty+j]);
}

// ---------------- transpose V: [bh][t][d] -> [bh][d][t] ----------------
__global__ __launch_bounds__(256) void k_transV(const unsigned short* __restrict__ v,
                                                unsigned short* __restrict__ vT){
  __shared__ unsigned short t[64][65];
  const int bh = blockIdx.y, t0 = blockIdx.x*64;
  const int tid = threadIdx.x;
  const size_t base = (size_t)bh*SEQ*HD;
  const int r = tid>>3, c = (tid&7)*8;
#pragma unroll
  for (int it=0; it<2; ++it){
    const int row = it*32 + r;
    s16x8 val = *(const s16x8*)(v + base + (size_t)(t0+row)*HD + c);
#pragma unroll
    for (int e=0;e<8;e++) t[row][c+e] = (unsigned short)val[e];
  }
  __syncthreads();
#pragma unroll
  for (int it=0; it<2; ++it){
    const int drow = it*32 + r;
    s16x8 o;
#pragma unroll
    for (int e=0;e<8;e++) o[e] = (short)t[c+e][drow];
    *(s16x8*)(vT + base + (size_t)drow*SEQ + t0 + c) = o;
  }
}

// ---------------- plain bf16 QKV GEMM: C[M,3072] = A[M,1024]*B^T + bias, RoPE, scatter ----
__global__ __launch_bounds__(256) void k_gemm(
    const unsigned short* __restrict__ A, const unsigned short* __restrict__ B,
    const float* __restrict__ bias, const float2* __restrict__ cstab,
    unsigned short* __restrict__ qb, unsigned short* __restrict__ kbp,
    unsigned short* __restrict__ vbp){
  __shared__ unsigned short sA[128*32];
  __shared__ unsigned short sB[128*32];
  const int tid = threadIdx.x;
  const int w = tid>>6, lane = tid&63;
  const int lr = lane&15, lk = lane>>4;
  const int wm = (w>>1)*64, wn = (w&1)*64;
  const int m0 = blockIdx.y*128, n0 = blockIdx.x*128;

  f32x4 acc[4][4];
#pragma unroll
  for (int m=0;m<4;m++)
#pragma unroll
    for (int n=0;n<4;n++) acc[m][n] = (f32x4){0.f,0.f,0.f,0.f};

  const int srow  = lane>>2;       // row within 16-row chunk
  const int sbyte = (lane&3)*16;   // byte col within 64B row

  for (int kt=0; kt<1024/32; ++kt){
    const int k0 = kt*32;
#pragma unroll
    for (int cc=0; cc<2; ++cc){
      const int chunk = w*2+cc;
      const int row = chunk*16 + srow;
      gload16((const char*)A + ((size_t)(m0+row)*1024 + k0)*2 + sbyte, (char*)sA + chunk*1024);
      gload16((const char*)B + ((size_t)(n0+row)*1024 + k0)*2 + sbyte, (char*)sB + chunk*1024);
    }
    __syncthreads();

    s16x8 ah[4], bh[4];
#pragma unroll
    for (int m=0;m<4;m++)
      ah[m] = *(const s16x8*)((const char*)sA + (wm + m*16 + lr)*64 + lk*16);
#pragma unroll
    for (int n=0;n<4;n++)
      bh[n] = *(const s16x8*)((const char*)sB + (wn + n*16 + lr)*64 + lk*16);
#pragma unroll
    for (int m=0;m<4;m++)
#pragma unroll
      for (int n=0;n<4;n++)
        acc[m][n] = MFMA(ah[m], bh[n], acc[m][n]);
    __syncthreads();
  }

#pragma unroll
  for (int m=0;m<4;m++)
#pragma unroll
    for (int n=0;n<4;n++)
#pragma unroll
      for (int r=0;r<4;r++){
        const int gm = m0 + wm + m*16 + lk*4 + r;
        const int gn = n0 + wn + n*16 + lr;
        float val = acc[m][n][r] + bias[gn];
        const int three = gn>>10, rem = gn&1023, h = rem>>6, d = rem&63;
        const int b = gm>>11, t = gm&2047;
        const float partner = __shfl_xor(val, 1);
        const size_t dst = ((size_t)(b*NHEAD + h))*SEQ*HD + (size_t)t*HD + d;
        if (three < 2){
          const float2 cs = cstab[t*32 + (d>>1)];
          float o;
          if (d & 1) o = partner*cs.y + val*cs.x;   // im' = re*sin + im*cos
          else       o = val*cs.x - partner*cs.y;   // re' = re*cos - im*sin
          if (three==0) qb[dst] = f2bf(o*QSCALE);
          else          kbp[dst] = f2bf(o);
        } else {
          vbp[dst] = f2bf(val);
        }
      }
}

// ---------------- proj GEMM: out[4096,1024] = A[4096,1024]*B^T + bias (fp32 out) ----------------
__global__ __launch_bounds__(256) void k_gemmP(
    const unsigned short* __restrict__ A, const unsigned short* __restrict__ B,
    const float* __restrict__ bias, float* __restrict__ outp){
  __shared__ unsigned short sA[128*32];
  __shared__ unsigned short sB[64*32];
  const int tid = threadIdx.x;
  const int w = tid>>6, lane = tid&63;
  const int lr = lane&15, lk = lane>>4;
  const int m0 = blockIdx.y*128, n0 = blockIdx.x*64;

  f32x4 acc[2][4];
#pragma unroll
  for (int m=0;m<2;m++)
#pragma unroll
    for (int n=0;n<4;n++) acc[m][n] = (f32x4){0.f,0.f,0.f,0.f};

  const int srow  = lane>>2;
  const int sbyte = (lane&3)*16;

  for (int kt=0; kt<1024/32; ++kt){
    const int k0 = kt*32;
#pragma unroll
    for (int cc=0; cc<2; ++cc){
      const int chunk = w*2+cc;
      const int row = chunk*16 + srow;
      gload16((const char*)A + ((size_t)(m0+row)*1024 + k0)*2 + sbyte,
              (char*)sA + chunk*1024);
    }
    {
      const int row = w*16 + srow;
      gload16((const char*)B + ((size_t)(n0+row)*1024 + k0)*2 + sbyte,
              (char*)sB + w*1024);
    }
    __syncthreads();

    s16x8 ah[2], bh[4];
#pragma unroll
    for (int m=0;m<2;m++)
      ah[m] = *(const s16x8*)((const char*)sA + (w*32 + m*16 + lr)*64 + lk*16);
#pragma unroll
    for (int n=0;n<4;n++)
      bh[n] = *(const s16x8*)((const char*)sB + (n*16 + lr)*64 + lk*16);
#pragma unroll
    for (int m=0;m<2;m++)
#pragma unroll
      for (int n=0;n<4;n++)
        acc[m][n] = MFMA(ah[m], bh[n], acc[m][n]);
    __syncthreads();
  }

#pragma unroll
  for (int m=0;m<2;m++)
#pragma unroll
    for (int n=0;n<4;n++)
#pragma unroll
      for (int r=0;r<4;r++){
        const int gm = m0 + w*32 + m*16 + lk*4 + r;
        const int gn = n0 + n*16 + lr;
        outp[(size_t)gm*DIM + gn] = acc[m][n][r] + bias[gn];
      }
}

// ---------------- flash attention: K/V register ping-pong prefetch ----------------
#define LOADK(kv, K0, K1) { \
  const unsigned short* kp_ = kbase + (size_t)((kv)+col)*HD + hi*8; \
  _Pragma("unroll") \
  for (int hb=0; hb<4; hb++){ \
    K0[hb] = *(const s16x8*)(kp_ + hb*16); \
    K1[hb] = *(const s16x8*)(kp_ + 32*HD + hb*16); } }

#define LOADV(kv, V0, V1) { \
  const unsigned short* vp_ = vbase + (size_t)col*SEQ + (kv) + hi*8; \
  _Pragma("unroll") \
  for (int mk=0; mk<4; mk++){ \
    V0[mk] = *(const s16x8*)(vp_ + mk*16); \
    V1[mk] = *(const s16x8*)(vp_ + (size_t)32*SEQ + mk*16); } }

#define TILE(K0c, K1c, V0c, V1c, kvn, K0n, K1n, V0n, V1n) { \
  f32x16 a0 = zero16(), a1 = zero16(); \
  __builtin_amdgcn_s_setprio(1); \
  _Pragma("unroll") \
  for (int hb=0; hb<4; hb++){ \
    a0 = MFMA32(K0c[hb], qf[hb], a0); \
    a1 = MFMA32(K1c[hb], qf[hb], a1); } \
  __builtin_amdgcn_s_setprio(0); \
  LOADK(kvn, K0n, K1n); \
  LOADV(kvn, V0n, V1n); \
  float pm0 = fmaxf(a0[0], a0[1]), pm1 = fmaxf(a0[2], a0[3]); \
  _Pragma("unroll") \
  for (int i=4;i<16;i+=2){ pm0 = fmaxf(pm0, a0[i]); pm1 = fmaxf(pm1, a0[i+1]); } \
  _Pragma("unroll") \
  for (int i=0;i<16;i+=2){ pm0 = fmaxf(pm0, a1[i]); pm1 = fmaxf(pm1, a1[i+1]); } \
  float pm = fmaxf(pm0, pm1); \
  pm = fmaxf(pm, __shfl_xor(pm, 32)); \
  if (!__all(pm - m <= 8.0f)){ \
    const float mn = fmaxf(m, pm); \
    const float al = __builtin_amdgcn_exp2f(m - mn); \
    l *= al; \
    _Pragma("unroll") \
    for (int i=0;i<16;i++){ o0[i] *= al; o1[i] *= al; } \
    m = mn; \
  } \
  _Pragma("unroll") \
  for (int i=0;i<16;i++){ \
    a0[i] = __builtin_amdgcn_exp2f(a0[i] - m); \
    a1[i] = __builtin_amdgcn_exp2f(a1[i] - m); } \
  float rs = 0.f; \
  _Pragma("unroll") \
  for (int i=0;i<16;i++) rs += a0[i] + a1[i]; \
  rs += __shfl_xor(rs, 32); \
  l += rs; \
  unsigned int pfd[4][4]; \
  _Pragma("unroll") \
  for (int kb2=0; kb2<4; kb2++){ \
    float cc[8]; \
    _Pragma("unroll") \
    for (int j=0;j<8;j++) cc[j] = (kb2<2) ? a0[(kb2&1)*8+j] : a1[(kb2&1)*8+j]; \
    unsigned int lo0 = cvtpk(cc[0],cc[1]), lo1 = cvtpk(cc[2],cc[3]); \
    unsigned int h0  = cvtpk(cc[4],cc[5]), h1  = cvtpk(cc[6],cc[7]); \
    unsigned int sl0 = (unsigned int)__shfl_xor((int)lo0, 32); \
    unsigned int sl1 = (unsigned int)__shfl_xor((int)lo1, 32); \
    unsigned int sh0 = (unsigned int)__shfl_xor((int)h0, 32); \
    unsigned int sh1 = (unsigned int)__shfl_xor((int)h1, 32); \
    pfd[kb2][0] = hi ? sh0 : lo0; \
    pfd[kb2][1] = hi ? sh1 : lo1; \
    pfd[kb2][2] = hi ? h0  : sl0; \
    pfd[kb2][3] = hi ? h1  : sl1; } \
  __builtin_amdgcn_s_setprio(1); \
  _Pragma("unroll") \
  for (int mk=0; mk<4; mk++){ \
    u32x4 dd = {pfd[mk][0], pfd[mk][1], pfd[mk][2], pfd[mk][3]}; \
    s16x8 pa = __builtin_bit_cast(s16x8, dd); \
    o0 = MFMA32(pa, V0c[mk], o0); \
    o1 = MFMA32(pa, V1c[mk], o1); } \
  __builtin_amdgcn_s_setprio(0); }

__global__ __launch_bounds__(256, 2) void k_attn(const unsigned short* __restrict__ qb,
                                                 const unsigned short* __restrict__ kb,
                                                 const unsigned short* __restrict__ vTb,
                                                 unsigned short* __restrict__ ao){
  __shared__ float l_tab[4][32];
  const int flat = blockIdx.x;
  const int wi = (flat & 7)*64 + (flat >> 3);   // XCD swizzle (512 blocks)
  const int bh = wi >> 4, qt = wi & 15;
  const int wid = threadIdx.x >> 6, lane = threadIdx.x & 63;
  const int col = lane & 31, hi = lane >> 5;
  const size_t base = (size_t)bh*SEQ*HD;
  const int q0 = qt*128 + wid*32;
  const unsigned short* kbase = kb + base;
  const unsigned short* vbase = vTb + base;

  s16x8 qf[4];
  {
    const unsigned short* qp = qb + base + (size_t)(q0+col)*HD + hi*8;
#pragma unroll
    for (int hb=0;hb<4;hb++) qf[hb] = *(const s16x8*)(qp + hb*16);
  }

  f32x16 o0 = zero16(), o1 = zero16();
  float m = -INFINITY, l = 0.f;

  s16x8 kf0A[4], kf1A[4], vf0A[4], vf1A[4];
  s16x8 kf0B[4], kf1B[4], vf0B[4], vf1B[4];

  LOADK(0, kf0A, kf1A);
  LOADV(0, vf0A, vf1A);

  for (int kv0 = 0; kv0 < SEQ; kv0 += 128){
    TILE(kf0A, kf1A, vf0A, vf1A, kv0+64, kf0B, kf1B, vf0B, vf1B);
    TILE(kf0B, kf1B, vf0B, vf1B, (kv0+128)&(SEQ-1), kf0A, kf1A, vf0A, vf1A);
  }

  l_tab[wid][col] = 1.0f / l;
  const int b = bh >> 4, h = bh & 15;
#pragma unroll
  for (int r=0;r<16;r++){
    const int qloc = (r&3) + 8*(r>>2) + 4*hi;
    const float linv = l_tab[wid][qloc];
    const int tq = q0 + qloc;
    const size_t drow = ((size_t)(b*SEQ + tq))*DIM + h*HD + col;
    ao[drow]      = f2bf(o0[r] * linv);
    ao[drow + 32] = f2bf(o1[r] * linv);
  }
}

extern "C" void kernel_launch(void* const* d_in, const int* in_sizes, int n_in,
                              void* d_out, int out_size, void* d_ws, size_t ws_size,
                              hipStream_t stream){
  const float* x     = (const float*)d_in[0];
  const float* Wqkv  = (const float*)d_in[1];
  const float* bqkv  = (const float*)d_in[2];
  const float* Wproj = (const float*)d_in[3];
  const float* bproj = (const float*)d_in[4];
  float* out = (float*)d_out;

  char* ws = (char*)d_ws;
  size_t off = 0;
  auto alloc = [&](size_t bytes)->char*{
    char* p = ws + off; off += (bytes + 255) & ~(size_t)255; return p;
  };
  unsigned short* xb    = (unsigned short*)alloc((size_t)NT*DIM*2);
  unsigned short* wqT   = (unsigned short*)alloc((size_t)N3*DIM*2);
  unsigned short* wpT   = (unsigned short*)alloc((size_t)DIM*DIM*2);
  unsigned short* q_bf  = (unsigned short*)alloc((size_t)NT*DIM*2);
  unsigned short* k_bf  = (unsigned short*)alloc((size_t)NT*DIM*2);
  unsigned short* v_bf  = (unsigned short*)alloc((size_t)NT*DIM*2);
  unsigned short* vT_bf = (unsigned short*)alloc((size_t)NT*DIM*2);
  unsigned short* ao_bf = (unsigned short*)alloc((size_t)NT*DIM*2);
  float2*         cstab = (float2*)alloc((size_t)SEQ*32*sizeof(float2));

  k_ropetab<<<SEQ*32/256, 256, 0, stream>>>(cstab);
  k_tobf<<<(NT*DIM/4)/256, 256, 0, stream>>>(x, xb, NT*DIM/4);
  k_transT<<<dim3(N3/32, DIM/32), dim3(32,8), 0, stream>>>(Wqkv, wqT, DIM, N3);
  k_transT<<<dim3(DIM/32, DIM/32), dim3(32,8), 0, stream>>>(Wproj, wpT, DIM, DIM);
  k_gemm<<<dim3(N3/128, NT/128), 256, 0, stream>>>(xb, wqT, bqkv, cstab, q_bf, k_bf, v_bf);
  k_transV<<<dim3(SEQ/64, BATCH*NHEAD), 256, 0, stream>>>(v_bf, vT_bf);
  k_attn<<<dim3(512), 256, 0, stream>>>(q_bf, k_bf, vT_bf, ao_bf);
  k_gemmP<<<dim3(DIM/64, NT/128), 256, 0, stream>>>(ao_bf, wpT, bproj, out);
}